// Round 2
// baseline (1303.052 us; speedup 1.0000x reference)
//
#include <hip/hip_runtime.h>
#include <hip/hip_bf16.h>

#define BLr 512
#define Dm 256
#define DIc 512
#define DOUTc 76416

typedef short bf16x8 __attribute__((ext_vector_type(8)));
typedef float f32x16 __attribute__((ext_vector_type(16)));

__device__ __forceinline__ unsigned short f2bf(float f){
  unsigned u = __builtin_bit_cast(unsigned, f);
  u += 0x7FFFu + ((u >> 16) & 1u);   // RNE
  return (unsigned short)(u >> 16);
}

__device__ __forceinline__ void gl_lds16(const void* g, void* l){
  __builtin_amdgcn_global_load_lds(
      (const __attribute__((address_space(1))) unsigned int*)g,
      (__attribute__((address_space(3))) unsigned int*)l, 16, 0, 0);
}

__device__ __forceinline__ bf16x8 cvt8(float4 a, float4 b){
  unsigned q0 = (unsigned)f2bf(a.x) | ((unsigned)f2bf(a.y) << 16);
  unsigned q1 = (unsigned)f2bf(a.z) | ((unsigned)f2bf(a.w) << 16);
  unsigned q2 = (unsigned)f2bf(b.x) | ((unsigned)f2bf(b.y) << 16);
  unsigned q3 = (unsigned)f2bf(b.z) | ((unsigned)f2bf(b.w) << 16);
  uint4 u{q0, q1, q2, q3};
  return __builtin_bit_cast(bf16x8, u);
}

// ---------------- init: resid = x ----------------
__global__ void init_resid_kernel(float* __restrict__ resid, const float* __restrict__ x){
  int i = blockIdx.x*256 + threadIdx.x;
  resid[i] = x[i];
}

// ---------------- K1: fused LN + in-proj. block = 32 rows x 64 cols ----------------
__global__ __launch_bounds__(256) void ln_inproj_kernel(
    float* __restrict__ xz, const float* __restrict__ resid,
    const float* __restrict__ lw, const float* __restrict__ lb,
    const float* __restrict__ iw)
{
  __shared__ __align__(16) float Aln[32][260];  // full K=256, LN'd
  __shared__ __align__(16) float Ws[64][36];    // 64 cols x 32 k chunk
  const int tid = threadIdx.x;
  const int m0 = blockIdx.y*32, n0 = blockIdx.x*64;
  const int wv = tid>>6, lane = tid&63;
  float4 w4 = *(const float4*)(lw + lane*4);
  float4 b4 = *(const float4*)(lb + lane*4);
  #pragma unroll
  for (int rr = 0; rr < 8; ++rr){
    int row = wv*8 + rr;
    float4 v = *(const float4*)(resid + (m0+row)*Dm + lane*4);
    float s  = v.x+v.y+v.z+v.w;
    float s2 = v.x*v.x+v.y*v.y+v.z*v.z+v.w*v.w;
    #pragma unroll
    for (int m = 1; m < 64; m <<= 1){ s += __shfl_xor(s,m); s2 += __shfl_xor(s2,m); }
    float mu = s*(1.f/256.f), var = s2*(1.f/256.f) - mu*mu;
    float rs = rsqrtf(var + 1e-5f);
    float4 o;
    o.x = (v.x-mu)*rs*w4.x + b4.x;
    o.y = (v.y-mu)*rs*w4.y + b4.y;
    o.z = (v.z-mu)*rs*w4.z + b4.z;
    o.w = (v.w-mu)*rs*w4.w + b4.w;
    *(float4*)&Aln[row][lane*4] = o;
  }
  const int ty = tid>>4, tx = tid&15;
  const int col = tid>>2, seg = tid&3;
  float acc[2][4] = {{0,0,0,0},{0,0,0,0}};
  for (int kc = 0; kc < 256; kc += 32){
    const float* wp = iw + (n0+col)*Dm + kc + seg*8;
    __syncthreads();   // also covers Aln writes on first pass
    *(float4*)&Ws[col][seg*8]   = *(const float4*)wp;
    *(float4*)&Ws[col][seg*8+4] = *(const float4*)(wp+4);
    __syncthreads();
    #pragma unroll
    for (int kk = 0; kk < 8; ++kk){
      float4 a0 = *(const float4*)&Aln[ty][kc+kk*4];
      float4 a1 = *(const float4*)&Aln[ty+16][kc+kk*4];
      #pragma unroll
      for (int j = 0; j < 4; ++j){
        float4 w = *(const float4*)&Ws[tx+16*j][kk*4];
        acc[0][j] += a0.x*w.x + a0.y*w.y + a0.z*w.z + a0.w*w.w;
        acc[1][j] += a1.x*w.x + a1.y*w.y + a1.z*w.z + a1.w*w.w;
      }
    }
  }
  #pragma unroll
  for (int j = 0; j < 4; ++j){
    xz[(m0+ty)*1024    + n0 + tx + 16*j] = acc[0][j];
    xz[(m0+ty+16)*1024 + n0 + tx + 16*j] = acc[1][j];
  }
}

// ---------------- K2: conv+SiLU + xproj + dt-proj. block = 1 row ----------------
__global__ __launch_bounds__(256) void conv_xproj_dt_kernel(
    float* __restrict__ xc, float* __restrict__ dbl, float* __restrict__ dtv,
    const float* __restrict__ xz, const float* __restrict__ cw,
    const float* __restrict__ cb, const float* __restrict__ xw,
    const float* __restrict__ dw, const float* __restrict__ db)
{
  __shared__ __align__(16) float xcr[512];
  __shared__ float dblq[16];
  const int row = blockIdx.x, tid = threadIdx.x;
  const int t = row & 255;
  #pragma unroll
  for (int h = 0; h < 2; ++h){
    int d = tid + h*256;
    float4 w = *(const float4*)(cw + d*4);
    float acc = cb[d];
    const float* xp = xz + (size_t)row*1024 + d;
    if (t >= 3) acc += w.x*xp[-3072] + w.y*xp[-2048] + w.z*xp[-1024] + w.w*xp[0];
    else {
      acc += w.w*xp[0];
      if (t >= 1) acc += w.z*xp[-1024];
      if (t >= 2) acc += w.y*xp[-2048];
    }
    float v = acc / (1.f + __expf(-acc));
    xcr[d] = v;
    xc[row*DIc + d] = v;
  }
  __syncthreads();
  const int wv = tid>>6, lane = tid&63;
  float4 xa = *(const float4*)&xcr[lane*4];
  float4 xb = *(const float4*)&xcr[256 + lane*4];
  for (int o = 0; o < 12; ++o){
    int oo = wv*12 + o;
    const float* wr = xw + oo*DIc;
    float4 wa = *(const float4*)(wr + lane*4);
    float4 wb = *(const float4*)(wr + 256 + lane*4);
    float p = xa.x*wa.x + xa.y*wa.y + xa.z*wa.z + xa.w*wa.w
            + xb.x*wb.x + xb.y*wb.y + xb.z*wb.z + xb.w*wb.w;
    #pragma unroll
    for (int m = 1; m < 64; m <<= 1) p += __shfl_xor(p, m);
    if (lane == 0){
      dbl[row*48 + oo] = p;
      if (oo < 16) dblq[oo] = p;
    }
  }
  __syncthreads();
  #pragma unroll
  for (int h = 0; h < 2; ++h){
    int d = tid + h*256;
    const float4* wr = (const float4*)(dw + d*16);
    float4 w0 = wr[0], w1 = wr[1], w2 = wr[2], w3 = wr[3];
    float acc = db[d];
    acc += dblq[0]*w0.x  + dblq[1]*w0.y  + dblq[2]*w0.z  + dblq[3]*w0.w;
    acc += dblq[4]*w1.x  + dblq[5]*w1.y  + dblq[6]*w1.z  + dblq[7]*w1.w;
    acc += dblq[8]*w2.x  + dblq[9]*w2.y  + dblq[10]*w2.z + dblq[11]*w2.w;
    acc += dblq[12]*w3.x + dblq[13]*w3.y + dblq[14]*w3.z + dblq[15]*w3.w;
    dtv[row*DIc + d] = (acc > 20.f) ? acc : log1pf(__expf(acc));
  }
}

// ---------------- K3: scan + spectral mix + gate. block = 8 channels x 1 batch ----------------
__global__ __launch_bounds__(256) void scan_fft_gate_kernel(
    float* __restrict__ g, unsigned short* __restrict__ gbf,
    const float* __restrict__ xc, const float* __restrict__ dtv,
    const float* __restrict__ dbl, const float* __restrict__ xz,
    const float* __restrict__ A_log, const float* __restrict__ Cmat,
    const float* __restrict__ Dvec, const float* __restrict__ sr,
    const float* __restrict__ si)
{
  __shared__ float xs[8][260], dts[8][260], ys[8][260];
  __shared__ float Bs[256][33];
  __shared__ float ct[256], st[256];
  __shared__ float Ysr[8][17], Ysi[8][17];
  const int tid = threadIdx.x;
  const int b = blockIdx.y, d0 = blockIdx.x*8;
  {
    float sv, cv;
    __sincosf((float)tid * 0.02454369260617026f, &sv, &cv);  // 2*pi/256
    ct[tid] = cv; st[tid] = sv;
  }
  const int dd = tid & 7, tq = tid >> 3;
  #pragma unroll
  for (int i = 0; i < 8; ++i){
    int t = i*32 + tq;
    xs[dd][t]  = xc [(b*256+t)*DIc + d0+dd];
    dts[dd][t] = dtv[(b*256+t)*DIc + d0+dd];
  }
  {
    int n = tid & 31, tb = tid >> 5;
    #pragma unroll 4
    for (int i = 0; i < 32; ++i){
      int t = i*8 + tb;
      Bs[t][n] = dbl[(b*256+t)*48 + 16 + n];
    }
  }
  __syncthreads();
  const int wv = tid>>6, lane = tid&63;
  {  // scan: wave = 2 channels x 32 states, all operands in LDS
    const int ddw = wv*2 + (lane>>5);
    const int d = d0 + ddw;
    const int n = lane & 31;
    const float A  = -__expf(A_log[d*32+n]);
    const float Cv = Cmat[d*32+n];
    float h = 0.f;
    #pragma unroll 4
    for (int t = 0; t < 256; ++t){
      float dtl = dts[ddw][t];
      float xv  = xs[ddw][t];
      float Bv  = Bs[t][n];
      h = __expf(dtl*A)*h + dtl*Bv*xv;
      float p = h*Cv;
      p += __shfl_xor(p,1); p += __shfl_xor(p,2); p += __shfl_xor(p,4);
      p += __shfl_xor(p,8); p += __shfl_xor(p,16);
      if (n == 0) ys[ddw][t] = p;
    }
  }
  {  // 16-bin DFT: wave = 2 channels x (16 bins x re/im)
    const int ddw = wv*2 + (lane>>5);
    const int m = lane & 15, im = (lane>>4) & 1;
    float acc = 0.f;
    for (int t = 0; t < 256; ++t){
      int idx = (m*t) & 255;
      acc += xs[ddw][t] * (im ? st[idx] : ct[idx]);
    }
    float other = __shfl_xor(acc, 16);
    const int d = d0 + ddw;
    float wr = sr[d*16+m], wi = si[d*16+m];
    if (im == 0){
      float Xr = acc, Xi = -other;
      Ysr[ddw][m] = Xr*wr - Xi*wi;
    } else {
      float Xi = -acc, Xr = other;
      Ysi[ddw][m] = Xr*wi + Xi*wr;
    }
  }
  __syncthreads();
  {  // synthesis + Dvec + gate, coalesced-ish write
    const float Dv = Dvec[d0+dd];
    float yr[16], yi[16];
    #pragma unroll
    for (int m = 0; m < 16; ++m){ yr[m] = Ysr[dd][m]; yi[m] = Ysi[dd][m]; }
    #pragma unroll 2
    for (int i = 0; i < 8; ++i){
      int t = i*32 + tq;
      float fv = 0.5f * yr[0];
      #pragma unroll
      for (int m = 1; m < 16; ++m){
        int idx = (m*t) & 255;
        fv += yr[m]*ct[idx] - yi[m]*st[idx];
      }
      float yv = ys[dd][t] + Dv*xs[dd][t] + fv*0.0078125f;
      float z = xz[(b*256+t)*1024 + 512 + d0+dd];
      float gv = yv * (z / (1.f + __expf(-z)));
      int oi = (b*256+t)*DIc + d0+dd;
      g[oi] = gv;
      gbf[oi] = f2bf(gv);
    }
  }
}

// ---------------- K4: out-proj + residual update. tile 32x32, K=512 ----------------
__global__ __launch_bounds__(256) void outproj_resid_kernel(
    float* __restrict__ resid, const float* __restrict__ g, const float* __restrict__ ow)
{
  __shared__ __align__(16) float As[32][36];
  __shared__ __align__(16) float Ws2[32][36];
  const int tid = threadIdx.x;
  const int n0 = blockIdx.x*32, m0 = blockIdx.y*32;
  const int r = tid>>3, c8 = (tid&7)*4;
  const int ty = tid>>4, tx = tid&15;
  float a00=0,a01=0,a10=0,a11=0;
  for (int kc = 0; kc < 512; kc += 32){
    __syncthreads();
    *(float4*)&As[r][c8]  = *(const float4*)(g  + (m0+r)*DIc + kc + c8);
    *(float4*)&Ws2[r][c8] = *(const float4*)(ow + (n0+r)*DIc + kc + c8);
    __syncthreads();
    #pragma unroll
    for (int kk = 0; kk < 8; ++kk){
      float4 a0 = *(const float4*)&As[ty][kk*4];
      float4 a1 = *(const float4*)&As[ty+16][kk*4];
      float4 w0 = *(const float4*)&Ws2[tx][kk*4];
      float4 w1 = *(const float4*)&Ws2[tx+16][kk*4];
      a00 += a0.x*w0.x + a0.y*w0.y + a0.z*w0.z + a0.w*w0.w;
      a01 += a0.x*w1.x + a0.y*w1.y + a0.z*w1.z + a0.w*w1.w;
      a10 += a1.x*w0.x + a1.y*w0.y + a1.z*w0.z + a1.w*w0.w;
      a11 += a1.x*w1.x + a1.y*w1.y + a1.z*w1.z + a1.w*w1.w;
    }
  }
  resid[(m0+ty)*Dm    + n0+tx]    += a00;
  resid[(m0+ty)*Dm    + n0+tx+16] += a01;
  resid[(m0+ty+16)*Dm + n0+tx]    += a10;
  resid[(m0+ty+16)*Dm + n0+tx+16] += a11;
}

// ---------------- K4f: final GEMM Out[512,76416] = G(bf16) @ W^T ----------------
// Block = 512 rows x 128 cols, 8 waves (4 rowg x 2 colg), wave tile 128x64 (4rt x 2ct).
// K-chunks of 64. A double-buffered in LDS (2x64KB) via global_load_lds + XOR swizzle
// (verified pattern). W: register-prefetch of next chunk + single 16KB LDS buffer.
// 2-phase schedule: next-chunk loads issued BEFORE current-chunk compute, so the
// __syncthreads() vmcnt drains land ~2300 cycles after issue (latency hidden).
__global__ __launch_bounds__(512) void gemm_final2_kernel(
    float* __restrict__ Out, const unsigned short* __restrict__ Gb,
    const float* __restrict__ W)
{
  __shared__ __align__(16) unsigned short As[2][32768];  // 2 x 64KB: 512 rows x 64 k
  __shared__ __align__(16) unsigned short Wb[8192];      // 16KB: 128 cols x 64 k (swizzled)
  const int tid = threadIdx.x;
  const int wv = tid>>6, lane = tid&63;
  const int half = lane>>5, lm = lane&31;
  const int colg = wv & 1, rowg = wv >> 1;
  const int n0 = blockIdx.x*128;
  // W staging: 4 threads per col, each covers 16 consecutive k (4 x float4)
  const int wcol = tid>>2, wseg = tid&3;
  const float* Wsrc = W + (size_t)(n0 + wcol)*512 + wseg*16;
  unsigned short* Wd0 = Wb + (wcol*8 + ((wseg*2)   ^ (wcol&7)))*8;
  unsigned short* Wd1 = Wb + (wcol*8 + ((wseg*2+1) ^ (wcol&7)))*8;

  f32x16 acc[4][2];
  #pragma unroll
  for (int rt = 0; rt < 4; ++rt)
    #pragma unroll
    for (int ct = 0; ct < 2; ++ct)
      #pragma unroll
      for (int rg = 0; rg < 16; ++rg) acc[rt][ct][rg] = 0.f;

  float4 wf[4];
  // ---- prologue: stage chunk 0 ----
  #pragma unroll
  for (int q = 0; q < 4; ++q) wf[q] = *(const float4*)(Wsrc + q*4);
  #pragma unroll
  for (int p = 0; p < 8; ++p){
    int R  = p*64 + wv*8;                       // wave-uniform base row
    int rr = R + (lane>>3);
    int cg = (lane&7) ^ (rr&7);
    gl_lds16(Gb + rr*512 + cg*8, (void*)((char*)&As[0][0] + R*128));
  }
  *(bf16x8*)Wd0 = cvt8(wf[0], wf[1]);
  *(bf16x8*)Wd1 = cvt8(wf[2], wf[3]);
  __syncthreads();

  int cur = 0;
  for (int t = 0; t < 8; ++t){
    const int k1 = (t+1)*64;
    if (t < 7){
      // prefetch next chunk: W -> regs, A -> other LDS buffer (in flight during compute)
      #pragma unroll
      for (int q = 0; q < 4; ++q) wf[q] = *(const float4*)(Wsrc + k1 + q*4);
      #pragma unroll
      for (int p = 0; p < 8; ++p){
        int R  = p*64 + wv*8;
        int rr = R + (lane>>3);
        int cg = (lane&7) ^ (rr&7);
        gl_lds16(Gb + rr*512 + k1 + cg*8, (void*)((char*)&As[cur^1][0] + R*128));
      }
    }
    // ---- compute chunk t ----
    #pragma unroll
    for (int j = 0; j < 4; ++j){
      const int c = j*2 + half;
      bf16x8 bv[2], av[4];
      #pragma unroll
      for (int ct = 0; ct < 2; ++ct){
        int wc = colg*64 + ct*32 + lm;
        bv[ct] = *(const bf16x8*)(Wb + (wc*8 + (c ^ (wc&7)))*8);
      }
      #pragma unroll
      for (int rt = 0; rt < 4; ++rt){
        int rr = rowg*128 + rt*32 + lm;
        av[rt] = *(const bf16x8*)((const char*)&As[cur][0] + (rr*8 + (c ^ (rr&7)))*16);
      }
      #pragma unroll
      for (int rt = 0; rt < 4; ++rt)
        #pragma unroll
        for (int ct = 0; ct < 2; ++ct)
          acc[rt][ct] = __builtin_amdgcn_mfma_f32_32x32x16_bf16(av[rt], bv[ct], acc[rt][ct], 0, 0, 0);
    }
    __syncthreads();            // all waves done reading Wb(t); prefetches long in flight
    if (t < 7){
      *(bf16x8*)Wd0 = cvt8(wf[0], wf[1]);
      *(bf16x8*)Wd1 = cvt8(wf[2], wf[3]);
    }
    __syncthreads();            // Wb(t+1) visible; A(t+1) gl_lds drained by vmcnt(0)
    cur ^= 1;
  }
  // ---- epilogue ----
  #pragma unroll
  for (int rt = 0; rt < 4; ++rt){
    const int rbase = rowg*128 + rt*32 + 4*half;
    #pragma unroll
    for (int ct = 0; ct < 2; ++ct){
      const int col = n0 + colg*64 + ct*32 + lm;
      #pragma unroll
      for (int rg = 0; rg < 16; ++rg){
        int row = rbase + (rg&3) + 8*(rg>>2);
        Out[(size_t)row*DOUTc + col] = acc[rt][ct][rg];
      }
    }
  }
}

// ---------------- host ----------------
extern "C" void kernel_launch(void* const* d_in, const int* in_sizes, int n_in,
                              void* d_out, int out_size, void* d_ws, size_t ws_size,
                              hipStream_t stream)
{
  (void)in_sizes; (void)n_in; (void)out_size; (void)ws_size;
  const float* x       = (const float*)d_in[0];
  const float* ln_w    = (const float*)d_in[1];
  const float* ln_b    = (const float*)d_in[2];
  const float* in_w    = (const float*)d_in[3];
  const float* conv_w  = (const float*)d_in[4];
  const float* conv_b  = (const float*)d_in[5];
  const float* xproj_w = (const float*)d_in[6];
  const float* dt_w    = (const float*)d_in[7];
  const float* dt_b    = (const float*)d_in[8];
  const float* A_log   = (const float*)d_in[9];
  const float* Cmat    = (const float*)d_in[10];
  const float* Dvec    = (const float*)d_in[11];
  const float* spec_r  = (const float*)d_in[12];
  const float* spec_i  = (const float*)d_in[13];
  const float* out_w   = (const float*)d_in[14];
  const float* fln_w   = (const float*)d_in[15];
  const float* fln_b   = (const float*)d_in[16];
  const float* f_in_w  = (const float*)d_in[17];
  const float* f_conv_w= (const float*)d_in[18];
  const float* f_conv_b= (const float*)d_in[19];
  const float* f_xproj = (const float*)d_in[20];
  const float* f_dt_w  = (const float*)d_in[21];
  const float* f_dt_b  = (const float*)d_in[22];
  const float* f_A_log = (const float*)d_in[23];
  const float* f_Cmat  = (const float*)d_in[24];
  const float* f_Dvec  = (const float*)d_in[25];
  const float* f_spec_r= (const float*)d_in[26];
  const float* f_spec_i= (const float*)d_in[27];
  const float* f_out_w = (const float*)d_in[28];

  float* ws   = (float*)d_ws;
  float* resid = ws;                      // 131072
  float* xz    = ws + 131072;             // 524288
  float* xcb   = ws + 655360;             // 262144
  float* dblb  = ws + 917504;             // 24576
  float* dtb   = ws + 942080;             // 262144
  float* gb    = ws + 1204224;            // 262144
  unsigned short* g_bf = (unsigned short*)(ws + 1466368);  // 262144 ushort
  float* outp = (float*)d_out;

  init_resid_kernel<<<512, 256, 0, stream>>>(resid, x);

  for (int i = 0; i < 8; ++i){
    const bool fin = (i == 7);
    const float* lw = fin ? fln_w   : ln_w    + i*256;
    const float* lb = fin ? fln_b   : ln_b    + i*256;
    const float* iw = fin ? f_in_w  : in_w    + i*262144;
    const float* cw = fin ? f_conv_w: conv_w  + i*2048;
    const float* cb = fin ? f_conv_b: conv_b  + i*512;
    const float* xw = fin ? f_xproj : xproj_w + i*24576;
    const float* dw = fin ? f_dt_w  : dt_w    + i*8192;
    const float* db = fin ? f_dt_b  : dt_b    + i*512;
    const float* al = fin ? f_A_log : A_log   + i*16384;
    const float* cm = fin ? f_Cmat  : Cmat    + i*16384;
    const float* dv = fin ? f_Dvec  : Dvec    + i*512;
    const float* sr = fin ? f_spec_r: spec_r  + i*8192;
    const float* si = fin ? f_spec_i: spec_i  + i*8192;

    ln_inproj_kernel<<<dim3(16, 16), 256, 0, stream>>>(xz, resid, lw, lb, iw);
    conv_xproj_dt_kernel<<<512, 256, 0, stream>>>(xcb, dblb, dtb, xz, cw, cb, xw, dw, db);
    scan_fft_gate_kernel<<<dim3(64, 2), 256, 0, stream>>>(gb, g_bf, xcb, dtb, dblb, xz,
                                                          al, cm, dv, sr, si);
    if (!fin){
      outproj_resid_kernel<<<dim3(8, 16), 256, 0, stream>>>(resid, gb, out_w + i*131072);
    } else {
      gemm_final2_kernel<<<DOUTc/128, 512, 0, stream>>>(outp, g_bf, f_out_w);
    }
  }
}

// Round 3
// 952.468 us; speedup vs baseline: 1.3681x; 1.3681x over previous
//
#include <hip/hip_runtime.h>
#include <hip/hip_bf16.h>

#define BLr 512
#define Dm 256
#define DIc 512
#define DOUTc 76416

typedef short bf16x8 __attribute__((ext_vector_type(8)));
typedef float f32x16 __attribute__((ext_vector_type(16)));

__device__ __forceinline__ unsigned short f2bf(float f){
  unsigned u = __builtin_bit_cast(unsigned, f);
  u += 0x7FFFu + ((u >> 16) & 1u);   // RNE
  return (unsigned short)(u >> 16);
}

__device__ __forceinline__ void gl_lds16(const void* g, void* l){
  __builtin_amdgcn_global_load_lds(
      (const __attribute__((address_space(1))) unsigned int*)g,
      (__attribute__((address_space(3))) unsigned int*)l, 16, 0, 0);
}

__device__ __forceinline__ bf16x8 cvt8(float4 a, float4 b){
  unsigned q0 = (unsigned)f2bf(a.x) | ((unsigned)f2bf(a.y) << 16);
  unsigned q1 = (unsigned)f2bf(a.z) | ((unsigned)f2bf(a.w) << 16);
  unsigned q2 = (unsigned)f2bf(b.x) | ((unsigned)f2bf(b.y) << 16);
  unsigned q3 = (unsigned)f2bf(b.z) | ((unsigned)f2bf(b.w) << 16);
  uint4 u{q0, q1, q2, q3};
  return __builtin_bit_cast(bf16x8, u);
}

// ---------------- init: resid = x ----------------
__global__ void init_resid_kernel(float* __restrict__ resid, const float* __restrict__ x){
  int i = blockIdx.x*256 + threadIdx.x;
  resid[i] = x[i];
}

// ---------------- K1: fused LN + in-proj. block = 32 rows x 64 cols ----------------
// v2: full 64KB W tile staged ONCE via global_load_lds (XOR-swizzled source so the
// b128 compute reads are bank-spread), single barrier, straight-line K=256 loop.
__global__ __launch_bounds__(256) void ln_inproj_kernel(
    float* __restrict__ xz, const float* __restrict__ resid,
    const float* __restrict__ lw, const float* __restrict__ lb,
    const float* __restrict__ iw)
{
  __shared__ __align__(16) float Aln[32][260];   // 32 rows x 256 LN'd (+pad)
  __shared__ __align__(16) float Wf[64*256];     // 64 cols x 256 k, 16B-chunk swizzled
  const int tid = threadIdx.x;
  const int m0 = blockIdx.y*32, n0 = blockIdx.x*64;
  const int wv = tid>>6, lane = tid&63;
  // ---- issue async W staging first: wave w covers cols {i*4+w} ----
  #pragma unroll
  for (int i = 0; i < 16; ++i){
    int col = i*4 + wv;
    int sc  = lane ^ (col&7);                        // pre-swizzled source chunk
    gl_lds16(iw + (size_t)(n0+col)*256 + sc*4, (void*)((char*)Wf + col*1024));
  }
  // ---- LN while W is in flight ----
  float4 w4 = *(const float4*)(lw + lane*4);
  float4 b4 = *(const float4*)(lb + lane*4);
  #pragma unroll
  for (int rr = 0; rr < 8; ++rr){
    int row = wv*8 + rr;
    float4 v = *(const float4*)(resid + (m0+row)*Dm + lane*4);
    float s  = v.x+v.y+v.z+v.w;
    float s2 = v.x*v.x+v.y*v.y+v.z*v.z+v.w*v.w;
    #pragma unroll
    for (int m = 1; m < 64; m <<= 1){ s += __shfl_xor(s,m); s2 += __shfl_xor(s2,m); }
    float mu = s*(1.f/256.f), var = s2*(1.f/256.f) - mu*mu;
    float rs = rsqrtf(var + 1e-5f);
    float4 o;
    o.x = (v.x-mu)*rs*w4.x + b4.x;
    o.y = (v.y-mu)*rs*w4.y + b4.y;
    o.z = (v.z-mu)*rs*w4.z + b4.z;
    o.w = (v.w-mu)*rs*w4.w + b4.w;
    *(float4*)&Aln[row][lane*4] = o;
  }
  __syncthreads();   // drains gl_lds (vmcnt0) + Aln writes
  const int ty = tid>>4, tx = tid&15;
  float acc[2][4] = {{0,0,0,0},{0,0,0,0}};
  #pragma unroll 4
  for (int kk = 0; kk < 64; ++kk){
    float4 a0 = *(const float4*)&Aln[ty][kk*4];
    float4 a1 = *(const float4*)&Aln[ty+16][kk*4];
    #pragma unroll
    for (int j = 0; j < 4; ++j){
      int col = tx + 16*j;
      float4 w = *(const float4*)&Wf[(col*64 + (kk ^ (col&7)))*4];
      acc[0][j] += a0.x*w.x + a0.y*w.y + a0.z*w.z + a0.w*w.w;
      acc[1][j] += a1.x*w.x + a1.y*w.y + a1.z*w.z + a1.w*w.w;
    }
  }
  #pragma unroll
  for (int j = 0; j < 4; ++j){
    xz[(m0+ty)*1024    + n0 + tx + 16*j] = acc[0][j];
    xz[(m0+ty+16)*1024 + n0 + tx + 16*j] = acc[1][j];
  }
}

// ---------------- K2: conv+SiLU + xproj + dt-proj. block = 1 row ----------------
__global__ __launch_bounds__(256) void conv_xproj_dt_kernel(
    float* __restrict__ xc, float* __restrict__ dbl, float* __restrict__ dtv,
    const float* __restrict__ xz, const float* __restrict__ cw,
    const float* __restrict__ cb, const float* __restrict__ xw,
    const float* __restrict__ dw, const float* __restrict__ db)
{
  __shared__ __align__(16) float xcr[512];
  __shared__ float dblq[16];
  const int row = blockIdx.x, tid = threadIdx.x;
  const int t = row & 255;
  #pragma unroll
  for (int h = 0; h < 2; ++h){
    int d = tid + h*256;
    float4 w = *(const float4*)(cw + d*4);
    float acc = cb[d];
    const float* xp = xz + (size_t)row*1024 + d;
    if (t >= 3) acc += w.x*xp[-3072] + w.y*xp[-2048] + w.z*xp[-1024] + w.w*xp[0];
    else {
      acc += w.w*xp[0];
      if (t >= 1) acc += w.z*xp[-1024];
      if (t >= 2) acc += w.y*xp[-2048];
    }
    float v = acc / (1.f + __expf(-acc));
    xcr[d] = v;
    xc[row*DIc + d] = v;
  }
  __syncthreads();
  const int wv = tid>>6, lane = tid&63;
  float4 xa = *(const float4*)&xcr[lane*4];
  float4 xb = *(const float4*)&xcr[256 + lane*4];
  for (int o = 0; o < 12; ++o){
    int oo = wv*12 + o;
    const float* wr = xw + oo*DIc;
    float4 wa = *(const float4*)(wr + lane*4);
    float4 wb = *(const float4*)(wr + 256 + lane*4);
    float p = xa.x*wa.x + xa.y*wa.y + xa.z*wa.z + xa.w*wa.w
            + xb.x*wb.x + xb.y*wb.y + xb.z*wb.z + xb.w*wb.w;
    #pragma unroll
    for (int m = 1; m < 64; m <<= 1) p += __shfl_xor(p, m);
    if (lane == 0){
      dbl[row*48 + oo] = p;
      if (oo < 16) dblq[oo] = p;
    }
  }
  __syncthreads();
  #pragma unroll
  for (int h = 0; h < 2; ++h){
    int d = tid + h*256;
    const float4* wr = (const float4*)(dw + d*16);
    float4 w0 = wr[0], w1 = wr[1], w2 = wr[2], w3 = wr[3];
    float acc = db[d];
    acc += dblq[0]*w0.x  + dblq[1]*w0.y  + dblq[2]*w0.z  + dblq[3]*w0.w;
    acc += dblq[4]*w1.x  + dblq[5]*w1.y  + dblq[6]*w1.z  + dblq[7]*w1.w;
    acc += dblq[8]*w2.x  + dblq[9]*w2.y  + dblq[10]*w2.z + dblq[11]*w2.w;
    acc += dblq[12]*w3.x + dblq[13]*w3.y + dblq[14]*w3.z + dblq[15]*w3.w;
    dtv[row*DIc + d] = (acc > 20.f) ? acc : log1pf(__expf(acc));
  }
}

// ---------------- K3: scan + spectral mix + gate ----------------
// v2: 4 channels/block -> 256 blocks (full GPU; was 128 = half idle).
// Scan reduction restructured: per 64-t pass, lanes dump h*Cv to wave-private LDS,
// then a batched n-reduction (32 reads/lane, conflict-free 67-pitch) replaces the
// serial 5-shfl chain per t (removes 1280 dependent DS ops per wave).
__global__ __launch_bounds__(128) void scan_fft_gate_kernel(
    float* __restrict__ g, unsigned short* __restrict__ gbf,
    const float* __restrict__ xc, const float* __restrict__ dtv,
    const float* __restrict__ dbl, const float* __restrict__ xz,
    const float* __restrict__ A_log, const float* __restrict__ Cmat,
    const float* __restrict__ Dvec, const float* __restrict__ sr,
    const float* __restrict__ si)
{
  __shared__ float xs[4][260], dts[4][260], ys[4][260];
  __shared__ float Bs[256][33];
  __shared__ float ct[256], st[256];
  __shared__ float Ysr[4][17], Ysi[4][17];
  __shared__ float Pl[2][2][32][67];   // [wave][ch][n][t-local pad 67]
  const int tid = threadIdx.x;
  const int b = blockIdx.y, d0 = blockIdx.x*4;
  #pragma unroll
  for (int k = 0; k < 2; ++k){
    int idx = tid + k*128;
    float sv, cv;
    __sincosf((float)idx * 0.02454369260617026f, &sv, &cv);  // 2*pi/256
    ct[idx] = cv; st[idx] = sv;
  }
  const int dd = tid & 3, tq = tid >> 2;      // tq 0..31
  #pragma unroll
  for (int i = 0; i < 8; ++i){
    int t = i*32 + tq;
    xs[dd][t]  = xc [(b*256+t)*DIc + d0+dd];
    dts[dd][t] = dtv[(b*256+t)*DIc + d0+dd];
  }
  {
    int n = tid & 31, tb = tid >> 5;          // tb 0..3
    #pragma unroll 8
    for (int i = 0; i < 64; ++i){
      int t = i*4 + tb;
      Bs[t][n] = dbl[(b*256+t)*48 + 16 + n];
    }
  }
  __syncthreads();
  const int wv = tid>>6, lane = tid&63;
  {  // scan: wave = 2 channels x 32 states; dump + batched reduce per 64-t pass
    const int ch2 = lane>>5;
    const int ddw = wv*2 + ch2;
    const int d = d0 + ddw;
    const int n = lane & 31;
    const int tloc = lane & 31;
    const float A  = -__expf(A_log[d*32+n]);
    const float Cv = Cmat[d*32+n];
    float h = 0.f;
    for (int pass = 0; pass < 4; ++pass){
      #pragma unroll 4
      for (int i = 0; i < 64; ++i){
        int t = pass*64 + i;
        float dtl = dts[ddw][t];
        float xv  = xs[ddw][t];
        float Bv  = Bs[t][n];
        h = __expf(dtl*A)*h + dtl*Bv*xv;
        Pl[wv][ch2][n][i] = h*Cv;
      }
      // wave-private region: no barrier needed, lgkmcnt ordering suffices
      float s0 = 0.f, s1 = 0.f;
      #pragma unroll 8
      for (int n2 = 0; n2 < 32; ++n2){
        s0 += Pl[wv][ch2][n2][tloc];
        s1 += Pl[wv][ch2][n2][32+tloc];
      }
      ys[ddw][pass*64 + tloc]      = s0;
      ys[ddw][pass*64 + 32 + tloc] = s1;
    }
  }
  {  // 16-bin DFT: wave = 2 channels x (16 bins x re/im)
    const int ddw = wv*2 + (lane>>5);
    const int m = lane & 15, im = (lane>>4) & 1;
    float acc = 0.f;
    for (int t = 0; t < 256; ++t){
      int idx = (m*t) & 255;
      acc += xs[ddw][t] * (im ? st[idx] : ct[idx]);
    }
    float other = __shfl_xor(acc, 16);
    const int d = d0 + ddw;
    float wr = sr[d*16+m], wi = si[d*16+m];
    if (im == 0){
      float Xr = acc, Xi = -other;
      Ysr[ddw][m] = Xr*wr - Xi*wi;
    } else {
      float Xi = -acc, Xr = other;
      Ysi[ddw][m] = Xr*wi + Xi*wr;
    }
  }
  __syncthreads();
  {  // synthesis + Dvec + gate
    const float Dv = Dvec[d0+dd];
    float yr[16], yi[16];
    #pragma unroll
    for (int m = 0; m < 16; ++m){ yr[m] = Ysr[dd][m]; yi[m] = Ysi[dd][m]; }
    #pragma unroll 2
    for (int i = 0; i < 8; ++i){
      int t = i*32 + tq;
      float fv = 0.5f * yr[0];
      #pragma unroll
      for (int m = 1; m < 16; ++m){
        int idx = (m*t) & 255;
        fv += yr[m]*ct[idx] - yi[m]*st[idx];
      }
      float yv = ys[dd][t] + Dv*xs[dd][t] + fv*0.0078125f;
      float z = xz[(b*256+t)*1024 + 512 + d0+dd];
      float gv = yv * (z / (1.f + __expf(-z)));
      int oi = (b*256+t)*DIc + d0+dd;
      g[oi] = gv;
      gbf[oi] = f2bf(gv);
    }
  }
}

// ---------------- K4: out-proj + residual update. tile 32m x 16n -> 256 blocks ----------------
__global__ __launch_bounds__(256) void outproj_resid_kernel(
    float* __restrict__ resid, const float* __restrict__ g, const float* __restrict__ ow)
{
  __shared__ __align__(16) float As[32][36];
  __shared__ __align__(16) float Ws2[16][36];
  const int tid = threadIdx.x;
  const int n0 = blockIdx.x*16, m0 = blockIdx.y*32;
  const int r = tid>>3, c8 = (tid&7)*4;
  const int ty = tid>>4, tx = tid&15;
  float a00=0, a10=0;
  for (int kc = 0; kc < 512; kc += 32){
    __syncthreads();
    *(float4*)&As[r][c8] = *(const float4*)(g + (m0+r)*DIc + kc + c8);
    if (tid < 128){
      *(float4*)&Ws2[tid>>3][c8] = *(const float4*)(ow + (n0+(tid>>3))*DIc + kc + c8);
    }
    __syncthreads();
    #pragma unroll
    for (int kk = 0; kk < 8; ++kk){
      float4 a0 = *(const float4*)&As[ty][kk*4];
      float4 a1 = *(const float4*)&As[ty+16][kk*4];
      float4 w0 = *(const float4*)&Ws2[tx][kk*4];
      a00 += a0.x*w0.x + a0.y*w0.y + a0.z*w0.z + a0.w*w0.w;
      a10 += a1.x*w0.x + a1.y*w0.y + a1.z*w0.z + a1.w*w0.w;
    }
  }
  resid[(m0+ty)*Dm    + n0+tx] += a00;
  resid[(m0+ty+16)*Dm + n0+tx] += a10;
}

// ---------------- K4f: final GEMM Out[512,76416] = G(bf16) @ W^T (R1, verified 108us) ----------------
__global__ __launch_bounds__(512) void gemm_final2_kernel(
    float* __restrict__ Out, const unsigned short* __restrict__ Gb,
    const float* __restrict__ W)
{
  __shared__ __align__(16) unsigned short As[32768];  // 64 KB: 512 rows x 64 k
  __shared__ __align__(16) unsigned short Wb[4096];   // 8 KB: 64 cols x 64 k (bf16, swizzled)
  const int tid = threadIdx.x;
  const int wv = tid>>6, lane = tid&63;
  const int half = lane>>5, lm = lane&31;
  const int nq = wv & 1, mq = wv >> 1;
  const int col = blockIdx.x*64 + nq*32 + lm;
  const int wcol = tid>>3, wkq = tid&7;
  const float* Wsrc = W + (size_t)(blockIdx.x*64 + wcol)*512 + wkq*8;
  unsigned short* Wdst = Wb + (wcol*8 + (wkq ^ (wcol&7)))*8;
  f32x16 acc[4];
  #pragma unroll
  for (int i = 0; i < 4; ++i)
    #pragma unroll
    for (int rg = 0; rg < 16; ++rg) acc[i][rg] = 0.f;

  for (int k0 = 0; k0 < 512; k0 += 64){
    float4 wf0 = *(const float4*)(Wsrc + k0);
    float4 wf1 = *(const float4*)(Wsrc + k0 + 4);
    #pragma unroll
    for (int p = 0; p < 8; ++p){
      int R  = p*64 + wv*8;
      int rr = R + (lane>>3);
      int cg = (lane&7) ^ (rr&7);
      gl_lds16(Gb + rr*512 + k0 + cg*8, (void*)((char*)As + R*128));
    }
    *(bf16x8*)Wdst = cvt8(wf0, wf1);
    __syncthreads();
    #pragma unroll
    for (int j = 0; j < 4; ++j){
      const int c = j*2 + half;
      bf16x8 bv = *(const bf16x8*)(Wb + (((nq*32+lm)*8) + (c ^ ((nq*32+lm)&7)))*8);
      #pragma unroll
      for (int mt = 0; mt < 4; ++mt){
        int rr = mq*128 + mt*32 + lm;
        bf16x8 av = *(const bf16x8*)((const char*)As + (rr*8 + (c ^ (rr&7)))*16);
        acc[mt] = __builtin_amdgcn_mfma_f32_32x32x16_bf16(av, bv, acc[mt], 0, 0, 0);
      }
    }
    __syncthreads();
  }
  #pragma unroll
  for (int mt = 0; mt < 4; ++mt){
    int rbase = mq*128 + mt*32 + 4*half;
    #pragma unroll
    for (int rg = 0; rg < 16; ++rg){
      int row = rbase + (rg&3) + 8*(rg>>2);
      Out[(size_t)row*DOUTc + col] = acc[mt][rg];
    }
  }
}

// ---------------- host ----------------
extern "C" void kernel_launch(void* const* d_in, const int* in_sizes, int n_in,
                              void* d_out, int out_size, void* d_ws, size_t ws_size,
                              hipStream_t stream)
{
  (void)in_sizes; (void)n_in; (void)out_size; (void)ws_size;
  const float* x       = (const float*)d_in[0];
  const float* ln_w    = (const float*)d_in[1];
  const float* ln_b    = (const float*)d_in[2];
  const float* in_w    = (const float*)d_in[3];
  const float* conv_w  = (const float*)d_in[4];
  const float* conv_b  = (const float*)d_in[5];
  const float* xproj_w = (const float*)d_in[6];
  const float* dt_w    = (const float*)d_in[7];
  const float* dt_b    = (const float*)d_in[8];
  const float* A_log   = (const float*)d_in[9];
  const float* Cmat    = (const float*)d_in[10];
  const float* Dvec    = (const float*)d_in[11];
  const float* spec_r  = (const float*)d_in[12];
  const float* spec_i  = (const float*)d_in[13];
  const float* out_w   = (const float*)d_in[14];
  const float* fln_w   = (const float*)d_in[15];
  const float* fln_b   = (const float*)d_in[16];
  const float* f_in_w  = (const float*)d_in[17];
  const float* f_conv_w= (const float*)d_in[18];
  const float* f_conv_b= (const float*)d_in[19];
  const float* f_xproj = (const float*)d_in[20];
  const float* f_dt_w  = (const float*)d_in[21];
  const float* f_dt_b  = (const float*)d_in[22];
  const float* f_A_log = (const float*)d_in[23];
  const float* f_Cmat  = (const float*)d_in[24];
  const float* f_Dvec  = (const float*)d_in[25];
  const float* f_spec_r= (const float*)d_in[26];
  const float* f_spec_i= (const float*)d_in[27];
  const float* f_out_w = (const float*)d_in[28];

  float* ws   = (float*)d_ws;
  float* resid = ws;                      // 131072
  float* xz    = ws + 131072;             // 524288
  float* xcb   = ws + 655360;             // 262144
  float* dblb  = ws + 917504;             // 24576
  float* dtb   = ws + 942080;             // 262144
  float* gb    = ws + 1204224;            // 262144
  unsigned short* g_bf = (unsigned short*)(ws + 1466368);  // 262144 ushort
  float* outp = (float*)d_out;

  init_resid_kernel<<<512, 256, 0, stream>>>(resid, x);

  for (int i = 0; i < 8; ++i){
    const bool fin = (i == 7);
    const float* lw = fin ? fln_w   : ln_w    + i*256;
    const float* lb = fin ? fln_b   : ln_b    + i*256;
    const float* iw = fin ? f_in_w  : in_w    + i*262144;
    const float* cw = fin ? f_conv_w: conv_w  + i*2048;
    const float* cb = fin ? f_conv_b: conv_b  + i*512;
    const float* xw = fin ? f_xproj : xproj_w + i*24576;
    const float* dw = fin ? f_dt_w  : dt_w    + i*8192;
    const float* db = fin ? f_dt_b  : dt_b    + i*512;
    const float* al = fin ? f_A_log : A_log   + i*16384;
    const float* cm = fin ? f_Cmat  : Cmat    + i*16384;
    const float* dv = fin ? f_Dvec  : Dvec    + i*512;
    const float* sr = fin ? f_spec_r: spec_r  + i*8192;
    const float* si = fin ? f_spec_i: spec_i  + i*8192;

    ln_inproj_kernel<<<dim3(16, 16), 256, 0, stream>>>(xz, resid, lw, lb, iw);
    conv_xproj_dt_kernel<<<512, 256, 0, stream>>>(xcb, dblb, dtb, xz, cw, cb, xw, dw, db);
    scan_fft_gate_kernel<<<dim3(128, 2), 128, 0, stream>>>(gb, g_bf, xcb, dtb, dblb, xz,
                                                           al, cm, dv, sr, si);
    if (!fin){
      outproj_resid_kernel<<<dim3(16, 16), 256, 0, stream>>>(resid, gb, out_w + i*131072);
    } else {
      gemm_final2_kernel<<<DOUTc/64, 512, 0, stream>>>(outp, g_bf, f_out_w);
    }
  }
}

// Round 4
// 844.859 us; speedup vs baseline: 1.5423x; 1.1274x over previous
//
#include <hip/hip_runtime.h>
#include <hip/hip_bf16.h>

#define BLr 512
#define Dm 256
#define DIc 512
#define DOUTc 76416

typedef short bf16x8 __attribute__((ext_vector_type(8)));
typedef float f32x16 __attribute__((ext_vector_type(16)));

__device__ __forceinline__ unsigned short f2bf(float f){
  unsigned u = __builtin_bit_cast(unsigned, f);
  u += 0x7FFFu + ((u >> 16) & 1u);   // RNE
  return (unsigned short)(u >> 16);
}

__device__ __forceinline__ void gl_lds16(const void* g, void* l){
  __builtin_amdgcn_global_load_lds(
      (const __attribute__((address_space(1))) unsigned int*)g,
      (__attribute__((address_space(3))) unsigned int*)l, 16, 0, 0);
}

__device__ __forceinline__ bf16x8 cvt8(float4 a, float4 b){
  unsigned q0 = (unsigned)f2bf(a.x) | ((unsigned)f2bf(a.y) << 16);
  unsigned q1 = (unsigned)f2bf(a.z) | ((unsigned)f2bf(a.w) << 16);
  unsigned q2 = (unsigned)f2bf(b.x) | ((unsigned)f2bf(b.y) << 16);
  unsigned q3 = (unsigned)f2bf(b.z) | ((unsigned)f2bf(b.w) << 16);
  uint4 u{q0, q1, q2, q3};
  return __builtin_bit_cast(bf16x8, u);
}

// ---------------- K1: fused LN + in-proj. block = 32 rows x 64 cols ----------------
// Full 64KB W tile staged ONCE via global_load_lds (XOR-swizzled source), single
// barrier, straight-line K=256 loop. src = x (layer 0) or resid.
__global__ __launch_bounds__(256) void ln_inproj_kernel(
    float* __restrict__ xz, const float* __restrict__ src,
    const float* __restrict__ lw, const float* __restrict__ lb,
    const float* __restrict__ iw)
{
  __shared__ __align__(16) float Aln[32][260];   // 32 rows x 256 LN'd (+pad)
  __shared__ __align__(16) float Wf[64*256];     // 64 cols x 256 k, 16B-chunk swizzled
  const int tid = threadIdx.x;
  const int m0 = blockIdx.y*32, n0 = blockIdx.x*64;
  const int wv = tid>>6, lane = tid&63;
  // ---- issue async W staging first: wave w covers cols {i*4+w} ----
  #pragma unroll
  for (int i = 0; i < 16; ++i){
    int col = i*4 + wv;
    int sc  = lane ^ (col&7);                        // pre-swizzled source chunk
    gl_lds16(iw + (size_t)(n0+col)*256 + sc*4, (void*)((char*)Wf + col*1024));
  }
  // ---- LN while W is in flight ----
  float4 w4 = *(const float4*)(lw + lane*4);
  float4 b4 = *(const float4*)(lb + lane*4);
  #pragma unroll
  for (int rr = 0; rr < 8; ++rr){
    int row = wv*8 + rr;
    float4 v = *(const float4*)(src + (m0+row)*Dm + lane*4);
    float s  = v.x+v.y+v.z+v.w;
    float s2 = v.x*v.x+v.y*v.y+v.z*v.z+v.w*v.w;
    #pragma unroll
    for (int m = 1; m < 64; m <<= 1){ s += __shfl_xor(s,m); s2 += __shfl_xor(s2,m); }
    float mu = s*(1.f/256.f), var = s2*(1.f/256.f) - mu*mu;
    float rs = rsqrtf(var + 1e-5f);
    float4 o;
    o.x = (v.x-mu)*rs*w4.x + b4.x;
    o.y = (v.y-mu)*rs*w4.y + b4.y;
    o.z = (v.z-mu)*rs*w4.z + b4.z;
    o.w = (v.w-mu)*rs*w4.w + b4.w;
    *(float4*)&Aln[row][lane*4] = o;
  }
  __syncthreads();   // drains gl_lds (vmcnt0) + Aln writes
  const int ty = tid>>4, tx = tid&15;
  float acc[2][4] = {{0,0,0,0},{0,0,0,0}};
  #pragma unroll 4
  for (int kk = 0; kk < 64; ++kk){
    float4 a0 = *(const float4*)&Aln[ty][kk*4];
    float4 a1 = *(const float4*)&Aln[ty+16][kk*4];
    #pragma unroll
    for (int j = 0; j < 4; ++j){
      int col = tx + 16*j;
      float4 w = *(const float4*)&Wf[(col*64 + (kk ^ (col&7)))*4];
      acc[0][j] += a0.x*w.x + a0.y*w.y + a0.z*w.z + a0.w*w.w;
      acc[1][j] += a1.x*w.x + a1.y*w.y + a1.z*w.z + a1.w*w.w;
    }
  }
  #pragma unroll
  for (int j = 0; j < 4; ++j){
    xz[(m0+ty)*1024    + n0 + tx + 16*j] = acc[0][j];
    xz[(m0+ty+16)*1024 + n0 + tx + 16*j] = acc[1][j];
  }
}

// ---------------- K2: conv+SiLU + xproj + dt-proj. block = 1 row ----------------
__global__ __launch_bounds__(256) void conv_xproj_dt_kernel(
    float* __restrict__ xc, float* __restrict__ dbl, float* __restrict__ dtv,
    const float* __restrict__ xz, const float* __restrict__ cw,
    const float* __restrict__ cb, const float* __restrict__ xw,
    const float* __restrict__ dw, const float* __restrict__ db)
{
  __shared__ __align__(16) float xcr[512];
  __shared__ float dblq[16];
  const int row = blockIdx.x, tid = threadIdx.x;
  const int t = row & 255;
  #pragma unroll
  for (int h = 0; h < 2; ++h){
    int d = tid + h*256;
    float4 w = *(const float4*)(cw + d*4);
    float acc = cb[d];
    const float* xp = xz + (size_t)row*1024 + d;
    if (t >= 3) acc += w.x*xp[-3072] + w.y*xp[-2048] + w.z*xp[-1024] + w.w*xp[0];
    else {
      acc += w.w*xp[0];
      if (t >= 1) acc += w.z*xp[-1024];
      if (t >= 2) acc += w.y*xp[-2048];
    }
    float v = acc / (1.f + __expf(-acc));
    xcr[d] = v;
    xc[row*DIc + d] = v;
  }
  __syncthreads();
  const int wv = tid>>6, lane = tid&63;
  float4 xa = *(const float4*)&xcr[lane*4];
  float4 xb = *(const float4*)&xcr[256 + lane*4];
  #pragma unroll
  for (int o = 0; o < 12; ++o){
    int oo = wv*12 + o;
    const float* wr = xw + oo*DIc;
    float4 wa = *(const float4*)(wr + lane*4);
    float4 wb = *(const float4*)(wr + 256 + lane*4);
    float p = xa.x*wa.x + xa.y*wa.y + xa.z*wa.z + xa.w*wa.w
            + xb.x*wb.x + xb.y*wb.y + xb.z*wb.z + xb.w*wb.w;
    #pragma unroll
    for (int m = 1; m < 64; m <<= 1) p += __shfl_xor(p, m);
    if (lane == 0){
      dbl[row*48 + oo] = p;
      if (oo < 16) dblq[oo] = p;
    }
  }
  __syncthreads();
  #pragma unroll
  for (int h = 0; h < 2; ++h){
    int d = tid + h*256;
    const float4* wr = (const float4*)(dw + d*16);
    float4 w0 = wr[0], w1 = wr[1], w2 = wr[2], w3 = wr[3];
    float acc = db[d];
    acc += dblq[0]*w0.x  + dblq[1]*w0.y  + dblq[2]*w0.z  + dblq[3]*w0.w;
    acc += dblq[4]*w1.x  + dblq[5]*w1.y  + dblq[6]*w1.z  + dblq[7]*w1.w;
    acc += dblq[8]*w2.x  + dblq[9]*w2.y  + dblq[10]*w2.z + dblq[11]*w2.w;
    acc += dblq[12]*w3.x + dblq[13]*w3.y + dblq[14]*w3.z + dblq[15]*w3.w;
    dtv[row*DIc + d] = (acc > 20.f) ? acc : log1pf(__expf(acc));
  }
}

// ---------------- K3: scan + spectral mix + gate ----------------
// v3: 256 threads, 4 channels/block, 256 blocks. Waves 0-1 run the scan while
// waves 2-3 run the (independent) DFT CONCURRENTLY -> critical path = max, not sum.
// Bs staging dropped (direct L2 reads of dbl, broadcast across half-waves).
// Pl pitch 65 (conflict-free). Synthesis uses all 256 threads.
__global__ __launch_bounds__(256) void scan_fft_gate_kernel(
    float* __restrict__ g, unsigned short* __restrict__ gbf,
    const float* __restrict__ xc, const float* __restrict__ dtv,
    const float* __restrict__ dbl, const float* __restrict__ xz,
    const float* __restrict__ A_log, const float* __restrict__ Cmat,
    const float* __restrict__ Dvec, const float* __restrict__ sr,
    const float* __restrict__ si)
{
  __shared__ float xs[4][260], dts[4][260], ys[4][260];
  __shared__ float ct[256], st[256];
  __shared__ float Ysr[4][17], Ysi[4][17];
  __shared__ float Pl[2][2][32][65];   // [scan-wave][ch][n][t-local], pitch 65
  const int tid = threadIdx.x;
  const int b = blockIdx.y, d0 = blockIdx.x*4;
  {
    float sv, cv;
    __sincosf((float)tid * 0.02454369260617026f, &sv, &cv);  // 2*pi/256
    ct[tid] = cv; st[tid] = sv;
  }
  const int dd = tid & 3, tq = tid >> 2;      // tq 0..63
  #pragma unroll
  for (int i = 0; i < 4; ++i){
    int t = i*64 + tq;
    xs[dd][t]  = xc [(b*256+t)*DIc + d0+dd];
    dts[dd][t] = dtv[(b*256+t)*DIc + d0+dd];
  }
  __syncthreads();
  const int wv = tid>>6, lane = tid&63;
  if (wv < 2){  // ---- scan waves: wave = 2 channels x 32 states ----
    const int ch2 = lane>>5;
    const int ddw = wv*2 + ch2;
    const int d = d0 + ddw;
    const int n = lane & 31;
    const int tloc = lane & 31;
    const float A  = -__expf(A_log[d*32+n]);
    const float Cv = Cmat[d*32+n];
    const float* Bp = dbl + (size_t)(b*256)*48 + 16 + n;
    float h = 0.f;
    for (int pass = 0; pass < 4; ++pass){
      #pragma unroll 8
      for (int i = 0; i < 64; ++i){
        int t = pass*64 + i;
        float dtl = dts[ddw][t];
        float xv  = xs[ddw][t];
        float Bv  = Bp[t*48];
        h = __expf(dtl*A)*h + dtl*Bv*xv;
        Pl[wv][ch2][n][i] = h*Cv;
      }
      // wave-private region: lgkmcnt ordering suffices, no barrier
      float s0 = 0.f, s1 = 0.f;
      #pragma unroll 8
      for (int n2 = 0; n2 < 32; ++n2){
        s0 += Pl[wv][ch2][n2][tloc];
        s1 += Pl[wv][ch2][n2][32+tloc];
      }
      ys[ddw][pass*64 + tloc]      = s0;
      ys[ddw][pass*64 + 32 + tloc] = s1;
    }
  } else {      // ---- DFT waves: wave = 2 channels x (16 bins x re/im) ----
    const int ddw = (wv-2)*2 + (lane>>5);
    const int m = lane & 15, im = (lane>>4) & 1;
    float acc = 0.f;
    for (int t = 0; t < 256; ++t){
      int idx = (m*t) & 255;
      acc += xs[ddw][t] * (im ? st[idx] : ct[idx]);
    }
    float other = __shfl_xor(acc, 16);
    const int d = d0 + ddw;
    float wr = sr[d*16+m], wi = si[d*16+m];
    if (im == 0){
      float Xr = acc, Xi = -other;
      Ysr[ddw][m] = Xr*wr - Xi*wi;
    } else {
      float Xi = -acc, Xr = other;
      Ysi[ddw][m] = Xr*wi + Xi*wr;
    }
  }
  __syncthreads();
  {  // synthesis + Dvec + gate, all 256 threads
    const float Dv = Dvec[d0+dd];
    float yr[16], yi[16];
    #pragma unroll
    for (int m = 0; m < 16; ++m){ yr[m] = Ysr[dd][m]; yi[m] = Ysi[dd][m]; }
    #pragma unroll 2
    for (int i = 0; i < 4; ++i){
      int t = i*64 + tq;
      float fv = 0.5f * yr[0];
      #pragma unroll
      for (int m = 1; m < 16; ++m){
        int idx = (m*t) & 255;
        fv += yr[m]*ct[idx] - yi[m]*st[idx];
      }
      float yv = ys[dd][t] + Dv*xs[dd][t] + fv*0.0078125f;
      float z = xz[(b*256+t)*1024 + 512 + d0+dd];
      float gv = yv * (z / (1.f + __expf(-z)));
      int oi = (b*256+t)*DIc + d0+dd;
      g[oi] = gv;
      gbf[oi] = f2bf(gv);
    }
  }
}

// ---------------- K4: out-proj + residual. tile 32m x 16n, W staged whole ----------------
// v3: full 32KB W tile + 16KB A chunks via global_load_lds with involution XOR
// swizzle (conflict-free b128 reads); 9 barriers instead of 32. Writes
// resid = base + acc (base = x at layer 0 -> init kernel eliminated).
__global__ __launch_bounds__(256) void outproj_resid_kernel(
    float* __restrict__ resid, const float* __restrict__ base,
    const float* __restrict__ g, const float* __restrict__ ow)
{
  __shared__ __align__(16) float Ws2[16*512];   // 32 KB, 16B-chunk swizzled per row
  __shared__ __align__(16) float As[32*128];    // 16 KB per k-chunk, swizzled
  const int tid = threadIdx.x;
  const int wv = tid>>6, lane = tid&63;
  const int n0 = blockIdx.x*16, m0 = blockIdx.y*32;
  const int ty = tid>>4, tx = tid&15;
  // stage full W tile once: wave w covers rows 4w..4w+3, 2 x 1KB per row
  #pragma unroll
  for (int i = 0; i < 4; ++i){
    int row = wv*4 + i;
    #pragma unroll
    for (int h = 0; h < 2; ++h){
      int c = h*64 + lane;
      int s = c ^ (row&7);
      gl_lds16(ow + (size_t)(n0+row)*DIc + s*4,
               (void*)((char*)Ws2 + row*2048 + h*1024));
    }
  }
  float b0 = base[(m0+ty)*Dm + n0+tx];
  float b1 = base[(m0+ty+16)*Dm + n0+tx];
  float a00 = 0.f, a10 = 0.f;
  for (int kc = 0; kc < 512; kc += 128){
    if (kc) __syncthreads();        // all waves done reading previous A chunk
    #pragma unroll
    for (int j = 0; j < 4; ++j){
      int R = wv*8 + j*2;           // wave-uniform base row (2 rows per gl_lds)
      int r = R + (lane>>5);
      int c = lane&31;
      int s = c ^ (r&7);
      gl_lds16(g + (size_t)(m0+r)*DIc + kc + s*4,
               (void*)((char*)As + R*512));
    }
    __syncthreads();                // drains gl_lds (W on first pass + A chunk)
    const int kb = kc>>2;
    #pragma unroll
    for (int kk = 0; kk < 32; ++kk){
      float4 a0 = *(const float4*)((const char*)As + ty*512      + ((kk ^ (ty&7))<<4));
      float4 a1 = *(const float4*)((const char*)As + (ty+16)*512 + ((kk ^ (ty&7))<<4));
      float4 w0 = *(const float4*)((const char*)Ws2 + tx*2048 + (((kb+kk) ^ (tx&7))<<4));
      a00 += a0.x*w0.x + a0.y*w0.y + a0.z*w0.z + a0.w*w0.w;
      a10 += a1.x*w0.x + a1.y*w0.y + a1.z*w0.z + a1.w*w0.w;
    }
  }
  resid[(m0+ty)*Dm    + n0+tx] = b0 + a00;
  resid[(m0+ty+16)*Dm + n0+tx] = b1 + a10;
}

// ---------------- K4f: final GEMM Out[512,76416] = G(bf16) @ W^T (R1, verified) ----------------
__global__ __launch_bounds__(512) void gemm_final2_kernel(
    float* __restrict__ Out, const unsigned short* __restrict__ Gb,
    const float* __restrict__ W)
{
  __shared__ __align__(16) unsigned short As[32768];  // 64 KB: 512 rows x 64 k
  __shared__ __align__(16) unsigned short Wb[4096];   // 8 KB: 64 cols x 64 k (bf16, swizzled)
  const int tid = threadIdx.x;
  const int wv = tid>>6, lane = tid&63;
  const int half = lane>>5, lm = lane&31;
  const int nq = wv & 1, mq = wv >> 1;
  const int col = blockIdx.x*64 + nq*32 + lm;
  const int wcol = tid>>3, wkq = tid&7;
  const float* Wsrc = W + (size_t)(blockIdx.x*64 + wcol)*512 + wkq*8;
  unsigned short* Wdst = Wb + (wcol*8 + (wkq ^ (wcol&7)))*8;
  f32x16 acc[4];
  #pragma unroll
  for (int i = 0; i < 4; ++i)
    #pragma unroll
    for (int rg = 0; rg < 16; ++rg) acc[i][rg] = 0.f;

  for (int k0 = 0; k0 < 512; k0 += 64){
    float4 wf0 = *(const float4*)(Wsrc + k0);
    float4 wf1 = *(const float4*)(Wsrc + k0 + 4);
    #pragma unroll
    for (int p = 0; p < 8; ++p){
      int R  = p*64 + wv*8;
      int rr = R + (lane>>3);
      int cg = (lane&7) ^ (rr&7);
      gl_lds16(Gb + rr*512 + k0 + cg*8, (void*)((char*)As + R*128));
    }
    *(bf16x8*)Wdst = cvt8(wf0, wf1);
    __syncthreads();
    #pragma unroll
    for (int j = 0; j < 4; ++j){
      const int c = j*2 + half;
      bf16x8 bv = *(const bf16x8*)(Wb + (((nq*32+lm)*8) + (c ^ ((nq*32+lm)&7)))*8);
      #pragma unroll
      for (int mt = 0; mt < 4; ++mt){
        int rr = mq*128 + mt*32 + lm;
        bf16x8 av = *(const bf16x8*)((const char*)As + (rr*8 + (c ^ (rr&7)))*16);
        acc[mt] = __builtin_amdgcn_mfma_f32_32x32x16_bf16(av, bv, acc[mt], 0, 0, 0);
      }
    }
    __syncthreads();
  }
  #pragma unroll
  for (int mt = 0; mt < 4; ++mt){
    int rbase = mq*128 + mt*32 + 4*half;
    #pragma unroll
    for (int rg = 0; rg < 16; ++rg){
      int row = rbase + (rg&3) + 8*(rg>>2);
      Out[(size_t)row*DOUTc + col] = acc[mt][rg];
    }
  }
}

// ---------------- host ----------------
extern "C" void kernel_launch(void* const* d_in, const int* in_sizes, int n_in,
                              void* d_out, int out_size, void* d_ws, size_t ws_size,
                              hipStream_t stream)
{
  (void)in_sizes; (void)n_in; (void)out_size; (void)ws_size;
  const float* x       = (const float*)d_in[0];
  const float* ln_w    = (const float*)d_in[1];
  const float* ln_b    = (const float*)d_in[2];
  const float* in_w    = (const float*)d_in[3];
  const float* conv_w  = (const float*)d_in[4];
  const float* conv_b  = (const float*)d_in[5];
  const float* xproj_w = (const float*)d_in[6];
  const float* dt_w    = (const float*)d_in[7];
  const float* dt_b    = (const float*)d_in[8];
  const float* A_log   = (const float*)d_in[9];
  const float* Cmat    = (const float*)d_in[10];
  const float* Dvec    = (const float*)d_in[11];
  const float* spec_r  = (const float*)d_in[12];
  const float* spec_i  = (const float*)d_in[13];
  const float* out_w   = (const float*)d_in[14];
  const float* fln_w   = (const float*)d_in[15];
  const float* fln_b   = (const float*)d_in[16];
  const float* f_in_w  = (const float*)d_in[17];
  const float* f_conv_w= (const float*)d_in[18];
  const float* f_conv_b= (const float*)d_in[19];
  const float* f_xproj = (const float*)d_in[20];
  const float* f_dt_w  = (const float*)d_in[21];
  const float* f_dt_b  = (const float*)d_in[22];
  const float* f_A_log = (const float*)d_in[23];
  const float* f_Cmat  = (const float*)d_in[24];
  const float* f_Dvec  = (const float*)d_in[25];
  const float* f_spec_r= (const float*)d_in[26];
  const float* f_spec_i= (const float*)d_in[27];
  const float* f_out_w = (const float*)d_in[28];

  float* ws   = (float*)d_ws;
  float* resid = ws;                      // 131072
  float* xz    = ws + 131072;             // 524288
  float* xcb   = ws + 655360;             // 262144
  float* dblb  = ws + 917504;             // 24576
  float* dtb   = ws + 942080;             // 262144
  float* gb    = ws + 1204224;            // 262144
  unsigned short* g_bf = (unsigned short*)(ws + 1466368);  // 262144 ushort
  float* outp = (float*)d_out;

  for (int i = 0; i < 8; ++i){
    const bool fin = (i == 7);
    const float* lw = fin ? fln_w   : ln_w    + i*256;
    const float* lb = fin ? fln_b   : ln_b    + i*256;
    const float* iw = fin ? f_in_w  : in_w    + i*262144;
    const float* cw = fin ? f_conv_w: conv_w  + i*2048;
    const float* cb = fin ? f_conv_b: conv_b  + i*512;
    const float* xw = fin ? f_xproj : xproj_w + i*24576;
    const float* dw = fin ? f_dt_w  : dt_w    + i*8192;
    const float* db = fin ? f_dt_b  : dt_b    + i*512;
    const float* al = fin ? f_A_log : A_log   + i*16384;
    const float* cm = fin ? f_Cmat  : Cmat    + i*16384;
    const float* dv = fin ? f_Dvec  : Dvec    + i*512;
    const float* sr = fin ? f_spec_r: spec_r  + i*8192;
    const float* si = fin ? f_spec_i: spec_i  + i*8192;

    const float* src = (i == 0) ? x : resid;
    ln_inproj_kernel<<<dim3(16, 16), 256, 0, stream>>>(xz, src, lw, lb, iw);
    conv_xproj_dt_kernel<<<512, 256, 0, stream>>>(xcb, dblb, dtb, xz, cw, cb, xw, dw, db);
    scan_fft_gate_kernel<<<dim3(128, 2), 256, 0, stream>>>(gb, g_bf, xcb, dtb, dblb, xz,
                                                           al, cm, dv, sr, si);
    if (!fin){
      outproj_resid_kernel<<<dim3(16, 16), 256, 0, stream>>>(resid, (i == 0) ? x : resid,
                                                             gb, out_w + i*131072);
    } else {
      gemm_final2_kernel<<<DOUTc/64, 512, 0, stream>>>(outp, g_bf, f_out_w);
    }
  }
}